// Round 1
// 312.176 us; speedup vs baseline: 1.0069x; 1.0069x over previous
//
#include <hip/hip_runtime.h>
#include <hip/hip_bf16.h>
#include <math.h>

// Problem constants
constexpr int NN = 50000;   // nodes
constexpr int NE = 800000;  // edges (without self loops)
constexpr int ET = NE + NN; // edges + self loops
constexpr int FH = 128;     // HEADS*HID = feature width (also IN_CH)
constexpr int NHEAD = 4;
constexpr int NG = 64;      // graphs
constexpr int OC = 10;      // out channels
constexpr int NB = (NN + 255) / 256; // 196 scan blocks

// dst-partitioned scatter/count: 8 partitions (XCD-aligned via blockIdx%8)
constexpr int NPART = 8;
constexpr int PSZ = (NN + NPART - 1) / NPART; // 6250
constexpr int NCHUNK = 400;
constexpr int CHUNK = NE / NCHUNK;            // 2000

// W^T pack: [128 n][136 k] ushort, padded to 136 for LDS bank stagger
constexpr int WKP = 136;
constexpr int WPLANE = 128 * WKP;   // ushorts per plane (hi or lo)

constexpr int CNT_BLKS = NCHUNK * NPART;   // 3200 count/scatter blocks
constexpr int GEMM_GRID = (NN + 63) / 64;  // 782 gemm blocks

typedef __attribute__((ext_vector_type(8))) short short8;
typedef __attribute__((ext_vector_type(4))) float f32x4;

__device__ inline ushort f2bf_bits(float f) {
    union { __hip_bfloat16 h; ushort u; } c;
    c.h = __float2bfloat16(f);
    return c.u;
}

// ---------------------------------------------------------------------------
// W split-precision pack (both layers). wt layout: l1 hi | l1 lo | l2 hi | l2 lo
// Must precede the fused kernel (its gemm blocks read planes 0,1).
// ---------------------------------------------------------------------------
__global__ __launch_bounds__(256) void pack_kernel(const float* __restrict__ W1,
                                                   const float* __restrict__ W2,
                                                   ushort* __restrict__ wt) {
    int idx = blockIdx.x * 256 + threadIdx.x; // 0..32767
    int layer = idx >> 14;
    int k = (idx >> 7) & 127;
    int n = idx & 127;
    const float* W = layer ? W2 : W1;
    float f = W[k * 128 + n];
    ushort hb = f2bf_bits(f);
    union { ushort u; __hip_bfloat16 h; } c; c.u = hb;
    float lo = f - __bfloat162float(c.h);
    ushort* base = wt + layer * 2 * WPLANE;
    base[n * WKP + k] = hb;
    base[WPLANE + n * WKP + k] = f2bf_bits(lo);
}

// ---------------------------------------------------------------------------
// MFMA GEMM + attention epilogue.
// C/D layout: col=lane&15, row=quad*4+reg.
// ---------------------------------------------------------------------------
#define GEMM_EPILOGUE()                                                          \
    float as_[8], ad_[8];                                                        \
    _Pragma("unroll")                                                            \
    for (int t = 0; t < 8; ++t) {                                                \
        as_[t] = att_s[t * 16 + l16];                                            \
        ad_[t] = att_d[t * 16 + l16];                                            \
    }                                                                            \
    float hs[4][4], hd[4][4];                                                    \
    _Pragma("unroll")                                                            \
    for (int r = 0; r < 4; ++r) {                                                \
        int grow = row0 + quad * 4 + r;                                          \
        bool okr = (grow < NN);                                                  \
        _Pragma("unroll")                                                        \
        for (int h = 0; h < 4; ++h) {                                            \
            hs[r][h] = acc[2*h][r] * as_[2*h] + acc[2*h+1][r] * as_[2*h+1];      \
            hd[r][h] = acc[2*h][r] * ad_[2*h] + acc[2*h+1][r] * ad_[2*h+1];      \
        }                                                                        \
        if (okr) {                                                               \
            _Pragma("unroll")                                                    \
            for (int t = 0; t < 8; ++t)                                          \
                Hb[(size_t)grow * FH + t * 16 + l16] = __float2bfloat16(acc[t][r]); \
        }                                                                        \
    }                                                                            \
    _Pragma("unroll")                                                            \
    for (int o = 1; o < 16; o <<= 1) {                                           \
        _Pragma("unroll")                                                        \
        for (int r = 0; r < 4; ++r)                                              \
            _Pragma("unroll")                                                    \
            for (int h = 0; h < 4; ++h) {                                        \
                hs[r][h] += __shfl_xor(hs[r][h], o);                             \
                hd[r][h] += __shfl_xor(hd[r][h], o);                             \
            }                                                                    \
    }                                                                            \
    if (l16 == 0) {                                                              \
        _Pragma("unroll")                                                        \
        for (int r = 0; r < 4; ++r) {                                            \
            int grow = row0 + quad * 4 + r;                                      \
            if (grow < NN) {                                                     \
                *(float4*)&a_src[grow * NHEAD] = make_float4(hs[r][0], hs[r][1], hs[r][2], hs[r][3]); \
                *(float4*)&a_dst[grow * NHEAD] = make_float4(hd[r][0], hd[r][1], hd[r][2], hd[r][3]); \
            }                                                                    \
        }                                                                        \
    }

// ---------------------------------------------------------------------------
// Fused dispatch: blocks [0, CNT_BLKS) do the dst-partitioned degree count
// (int4-vectorized); blocks [CNT_BLKS, CNT_BLKS+GEMM_GRID) run layer-1 GEMM
// (f32 input, split-precision 3-MFMA). The two halves touch disjoint data,
// so they overlap: count is memory/atomic-bound, gemm is MFMA/LDS-bound.
// NOTE: the 69.6 KB LDS caps ALL blocks at 2/CU; count loads are int4 so the
// reduced occupancy still covers latency (2 iters x 4KB/wave per block).
// ---------------------------------------------------------------------------
__global__ __launch_bounds__(256) void fused_count_gemm_kernel(
    const int* __restrict__ ei, int* __restrict__ counts,
    const float* __restrict__ A, const ushort* __restrict__ wt,
    const float* __restrict__ att_s, const float* __restrict__ att_d,
    __hip_bfloat16* __restrict__ Hb, float* __restrict__ a_src, float* __restrict__ a_dst)
{
    __shared__ ushort Wlds[2 * WPLANE];
    if (blockIdx.x < CNT_BLKS) {
        const int part = blockIdx.x & 7;
        const int base = (blockIdx.x >> 3) * CHUNK;
        const int lo = part * PSZ, hi = lo + PSZ;
        const int4* dp = (const int4*)(ei + NE + base); // 16B-aligned: NE+base % 4 == 0
        for (int k = threadIdx.x; k < CHUNK / 4; k += 256) {
            int4 d4 = dp[k];
            int d[4] = {d4.x, d4.y, d4.z, d4.w};
#pragma unroll
            for (int j = 0; j < 4; ++j)
                if (d[j] >= lo && d[j] < hi) atomicAdd(&counts[d[j]], 1);
        }
        return;
    }

    // ---- layer-1 GEMM (f32 input) ----
    const int tid = threadIdx.x;
    {
        const uint4* s = (const uint4*)wt;
        uint4* d = (uint4*)Wlds;
        for (int i = tid; i < 2 * WPLANE / 8; i += 256) d[i] = s[i];
    }
    __syncthreads();

    const int wave = tid >> 6;
    const int lane = tid & 63;
    const int quad = lane >> 4;
    const int l16 = lane & 15;
    const int row0 = (blockIdx.x - CNT_BLKS) * 64 + wave * 16;

    f32x4 acc[8];
#pragma unroll
    for (int t = 0; t < 8; ++t) acc[t] = (f32x4){0.f, 0.f, 0.f, 0.f};

    int arow = row0 + l16; if (arow >= NN) arow = NN - 1;
    const float* ap = A + (size_t)arow * FH + quad * 8;

#pragma unroll
    for (int kc = 0; kc < 4; ++kc) {
        float4 x0 = *(const float4*)(ap + kc * 32);
        float4 x1 = *(const float4*)(ap + kc * 32 + 4);
        float av[8] = {x0.x, x0.y, x0.z, x0.w, x1.x, x1.y, x1.z, x1.w};
        short8 ah, al;
#pragma unroll
        for (int j = 0; j < 8; ++j) {
            ushort hb = f2bf_bits(av[j]);
            union { ushort u; __hip_bfloat16 h; } c; c.u = hb;
            float lo = av[j] - __bfloat162float(c.h);
            ah[j] = (short)hb;
            al[j] = (short)f2bf_bits(lo);
        }
        const int kof = kc * 32 + quad * 8;
#pragma unroll
        for (int t = 0; t < 8; ++t) {
            const ushort* wp = &Wlds[(t * 16 + l16) * WKP + kof];
            short8 wh = *(const short8*)wp;
            short8 wl = *(const short8*)(wp + WPLANE);
            acc[t] = __builtin_amdgcn_mfma_f32_16x16x32_bf16(ah, wh, acc[t], 0, 0, 0);
            acc[t] = __builtin_amdgcn_mfma_f32_16x16x32_bf16(al, wh, acc[t], 0, 0, 0);
            acc[t] = __builtin_amdgcn_mfma_f32_16x16x32_bf16(ah, wl, acc[t], 0, 0, 0);
        }
    }
    GEMM_EPILOGUE()
}

__global__ __launch_bounds__(256) void partial_kernel(const int* __restrict__ counts,
                                                      int* __restrict__ bsum) {
    __shared__ int sd[256];
    const int t = threadIdx.x, n = blockIdx.x * 256 + t;
    int v = (n < NN) ? counts[n] + 1 : 0;
    sd[t] = v; __syncthreads();
#pragma unroll
    for (int o = 128; o > 0; o >>= 1) {
        if (t < o) sd[t] += sd[t + o];
        __syncthreads();
    }
    if (t == 0) bsum[blockIdx.x] = sd[0];
}

// write_offs with inlined block-sum scan; also writes the self-loop entry.
__global__ __launch_bounds__(256) void write_offs_kernel(const int* __restrict__ counts,
                                                         const int* __restrict__ bsum,
                                                         int* __restrict__ offs,
                                                         int* __restrict__ cursor,
                                                         int* __restrict__ csrc) {
    __shared__ int sd[256];
    __shared__ int bprefix;
    const int t = threadIdx.x, n = blockIdx.x * 256 + t;
    int bv = (t < NB) ? bsum[t] : 0;
    sd[t] = bv; __syncthreads();
#pragma unroll
    for (int o = 1; o < 256; o <<= 1) {
        int u = (t >= o) ? sd[t - o] : 0;
        __syncthreads();
        sd[t] += u;
        __syncthreads();
    }
    if (t == (int)blockIdx.x) bprefix = sd[t] - bv;
    __syncthreads();
    const int bpre = bprefix;
    __syncthreads();
    int v = (n < NN) ? counts[n] + 1 : 0;
    sd[t] = v; __syncthreads();
#pragma unroll
    for (int o = 1; o < 256; o <<= 1) {
        int u = (t >= o) ? sd[t - o] : 0;
        __syncthreads();
        sd[t] += u;
        __syncthreads();
    }
    int ex = sd[t] - v + bpre;
    if (n < NN) {
        offs[n] = ex; cursor[n] = ex;
        csrc[ex + v - 1] = n;   // self loop at end of the node's range
    }
    if (n == NN - 1) offs[NN] = ex + v; // == ET
}

__global__ __launch_bounds__(256) void scatter_kernel(const int* __restrict__ ei,
                                                      int* __restrict__ cursor,
                                                      int* __restrict__ csrc) {
    const int part = blockIdx.x & 7;
    const int base = (blockIdx.x >> 3) * CHUNK;
    const int lo = part * PSZ, hi = lo + PSZ;
    const int4* dp = (const int4*)(ei + NE + base);
    for (int k = threadIdx.x; k < CHUNK / 4; k += 256) {
        int4 d4 = dp[k];
        int d[4] = {d4.x, d4.y, d4.z, d4.w};
        const int e0 = base + 4 * k;
#pragma unroll
        for (int j = 0; j < 4; ++j) {
            if (d[j] >= lo && d[j] < hi) {
                int pos = atomicAdd(&cursor[d[j]], 1);
                csrc[pos] = ei[e0 + j];
            }
        }
    }
}

__global__ __launch_bounds__(256) void gemm_att_bf16_kernel(
    const __hip_bfloat16* __restrict__ A, const ushort* __restrict__ wt,
    const float* __restrict__ att_s, const float* __restrict__ att_d,
    __hip_bfloat16* __restrict__ Hb, float* __restrict__ a_src, float* __restrict__ a_dst)
{
    __shared__ ushort Wlds[2 * WPLANE];
    const int tid = threadIdx.x;
    {
        const uint4* s = (const uint4*)wt;
        uint4* d = (uint4*)Wlds;
        for (int i = tid; i < 2 * WPLANE / 8; i += 256) d[i] = s[i];
    }
    __syncthreads();

    const int wave = tid >> 6;
    const int lane = tid & 63;
    const int quad = lane >> 4;
    const int l16 = lane & 15;
    const int row0 = blockIdx.x * 64 + wave * 16;

    f32x4 acc[8];
#pragma unroll
    for (int t = 0; t < 8; ++t) acc[t] = (f32x4){0.f, 0.f, 0.f, 0.f};

    int arow = row0 + l16; if (arow >= NN) arow = NN - 1;
    const __hip_bfloat16* ap = A + (size_t)arow * FH + quad * 8;

#pragma unroll
    for (int kc = 0; kc < 4; ++kc) {
        short8 ah = *(const short8*)(ap + kc * 32);
        const int kof = kc * 32 + quad * 8;
#pragma unroll
        for (int t = 0; t < 8; ++t) {
            const ushort* wp = &Wlds[(t * 16 + l16) * WKP + kof];
            short8 wh = *(const short8*)wp;
            short8 wl = *(const short8*)(wp + WPLANE);
            acc[t] = __builtin_amdgcn_mfma_f32_16x16x32_bf16(ah, wh, acc[t], 0, 0, 0);
            acc[t] = __builtin_amdgcn_mfma_f32_16x16x32_bf16(ah, wl, acc[t], 0, 0, 0);
        }
    }
    GEMM_EPILOGUE()
}

// ---------------------------------------------------------------------------
// Per-node aggregation, one wave per node, producer/consumer over 64-edge
// chunks.
// ---------------------------------------------------------------------------
__global__ __launch_bounds__(256) void gat_agg_kernel(
    const __hip_bfloat16* __restrict__ Hb, const float* __restrict__ asrc,
    const float* __restrict__ adst, const int* __restrict__ offs,
    const int* __restrict__ csrc, const float* __restrict__ bias,
    __hip_bfloat16* __restrict__ out)
{
    __shared__ float2 wbuf[4][4][65];
    const int wid = threadIdx.x >> 6;
    const int lane = threadIdx.x & 63;
    const int n = blockIdx.x * 4 + wid;
    if (n >= NN) return;

    const int beg = offs[n], end = offs[n + 1];
    const int hB = lane & 3;
    const int eslot = lane >> 2;
    const float adB = adst[n * NHEAD + hB];
    float2* wrow = wbuf[wid][hB];
    const int es = lane >> 4;
    const int fs = lane & 15;
    const int hC = fs >> 2;
    const int f8 = fs * 8;
    const float2* crow = wbuf[wid][hC];

    float d = 0.f;
    float acc[8];
#pragma unroll
    for (int i = 0; i < 8; ++i) acc[i] = 0.f;

    for (int cs = beg; cs < end; cs += 64) {
        int ce = end - cs; if (ce > 64) ce = 64;
        for (int k = eslot; k < ce; k += 16) {
            int s = csrc[cs + k];
            float e = asrc[s * NHEAD + hB] + adB;
            e = e > 0.f ? e : 0.2f * e;
            float w = __expf(e);
            d += w;
            wrow[k] = make_float2(w, __int_as_float(s));
        }
        __asm__ volatile("s_waitcnt lgkmcnt(0)" ::: "memory");
        const int n8 = (ce + 7) >> 3;
        for (int p = 0; p < n8; ++p) {
            int eA = 8 * p + es;
            int eB = eA + 4;
            float2 wsA = crow[eA < ce ? eA : 0];
            float2 wsB = crow[eB < ce ? eB : 0];
            float wA = eA < ce ? wsA.x : 0.f;
            float wB = eB < ce ? wsB.x : 0.f;
            int sA = __float_as_int(wsA.y);
            int sB = __float_as_int(wsB.y);
            union { uint4 u; __hip_bfloat162 b[4]; } cvA, cvB;
            cvA.u = *(const uint4*)&Hb[(size_t)sA * FH + f8];
            cvB.u = *(const uint4*)&Hb[(size_t)sB * FH + f8];
#pragma unroll
            for (int i = 0; i < 4; ++i) {
                float2 hA = __bfloat1622float2(cvA.b[i]);
                float2 hB2 = __bfloat1622float2(cvB.b[i]);
                acc[2 * i]     = fmaf(wA, hA.x, acc[2 * i]);
                acc[2 * i + 1] = fmaf(wA, hA.y, acc[2 * i + 1]);
                acc[2 * i]     = fmaf(wB, hB2.x, acc[2 * i]);
                acc[2 * i + 1] = fmaf(wB, hB2.y, acc[2 * i + 1]);
            }
        }
    }
#pragma unroll
    for (int o = 4; o < 64; o <<= 1) d += __shfl_xor(d, o);
#pragma unroll
    for (int i = 0; i < 8; ++i) {
        acc[i] += __shfl_xor(acc[i], 16);
        acc[i] += __shfl_xor(acc[i], 32);
    }
    const float inv = 1.0f / __shfl(d, hC);
    if (es == 0) {
        union { ushort u8[8]; uint4 u; } pk;
#pragma unroll
        for (int i = 0; i < 8; ++i) {
            float v = fmaxf(fmaf(acc[i], inv, bias[f8 + i]), 0.f);
            pk.u8[i] = f2bf_bits(v);
        }
        *(uint4*)&out[(size_t)n * FH + f8] = pk.u;
    }
}

// ---------------------------------------------------------------------------
// Mean pool (batch sorted, bf16 input): 32-node chunks, run-length local acc
// ---------------------------------------------------------------------------
__global__ __launch_bounds__(128) void pool_kernel(
    const __hip_bfloat16* __restrict__ X, const int* __restrict__ batch,
    float* __restrict__ sums, int* __restrict__ cnts)
{
    const int f = threadIdx.x;
    const int beg = blockIdx.x * 32;
    int end = beg + 32; if (end > NN) end = NN;
    if (beg >= NN) return;
    float local = 0.f;
    int cnt = 0;
    int cur = batch[beg];
    for (int n = beg; n < end; ++n) {
        int g = batch[n];
        if (g != cur) {
            atomicAdd(&sums[cur * FH + f], local);
            if (f == 0) atomicAdd(&cnts[cur], cnt);
            local = 0.f; cnt = 0; cur = g;
        }
        local += __bfloat162float(X[(size_t)n * FH + f]);
        ++cnt;
    }
    atomicAdd(&sums[cur * FH + f], local);
    if (f == 0) atomicAdd(&cnts[cur], cnt);
}

__global__ void final_kernel(const float* __restrict__ sums, const int* __restrict__ cnts,
                             const float* __restrict__ wl, const float* __restrict__ bl,
                             float* __restrict__ out)
{
    const int t = threadIdx.x;
    if (t >= NG * OC) return;
    const int g = t / OC, o = t % OC;
    float invc = 1.0f / fmaxf((float)cnts[g], 1.0f);
    float acc = 0.f;
    for (int k = 0; k < FH; ++k)
        acc = fmaf(sums[g * FH + k], wl[k * OC + o], acc);
    out[t] = acc * invc + bl[o];
}

// ---------------------------------------------------------------------------
extern "C" void kernel_launch(void* const* d_in, const int* in_sizes, int n_in,
                              void* d_out, int out_size, void* d_ws, size_t ws_size,
                              hipStream_t stream) {
    const float* x       = (const float*)d_in[0];
    const int*   ei      = (const int*)d_in[1];   // [2, NE]
    const int*   batch   = (const int*)d_in[2];
    const float* W1      = (const float*)d_in[3];
    const float* as1     = (const float*)d_in[4];
    const float* ad1     = (const float*)d_in[5];
    const float* b1      = (const float*)d_in[6];
    const float* W2      = (const float*)d_in[7];
    const float* as2     = (const float*)d_in[8];
    const float* ad2     = (const float*)d_in[9];
    const float* b2      = (const float*)d_in[10];
    const float* wlin    = (const float*)d_in[11];
    const float* blin    = (const float*)d_in[12];
    float* out = (float*)d_out;

    // workspace layout
    __hip_bfloat16* hbuf = (__hip_bfloat16*)d_ws;        // NN*FH bf16 (gemm out)
    __hip_bfloat16* abuf = hbuf + (size_t)NN * FH;       // NN*FH bf16 (agg out)
    float* asrc  = (float*)(abuf + (size_t)NN * FH);     // NN*4
    float* adst  = asrc + (size_t)NN * NHEAD;
    float* sums  = adst + (size_t)NN * NHEAD; // NG*FH
    int*   cnts  = (int*)(sums + NG * FH);    // NG
    int* counts  = cnts + NG;                 // NN  (sums|cnts|counts contiguous)
    int* offs    = counts + NN;               // NN+1
    int* cursor  = offs + NN + 1;             // NN
    int* csrc    = cursor + NN;               // ET
    int* bsum    = csrc + ET;                 // NB
    ushort* wt   = (ushort*)(((uintptr_t)(bsum + NB) + 15) & ~(uintptr_t)15); // 4*WPLANE

    // single zero init: sums + cnts + counts (contiguous)
    hipMemsetAsync(sums, 0, sizeof(float) * NG * FH + sizeof(int) * NG + sizeof(int) * NN, stream);

    // W pack first (fused kernel's gemm blocks read planes 0,1)
    pack_kernel<<<128, 256, 0, stream>>>(W1, W2, wt);

    // Fused: degree count + layer-1 GEMM (independent work, one dispatch)
    fused_count_gemm_kernel<<<CNT_BLKS + GEMM_GRID, 256, 0, stream>>>(
        ei, counts, x, wt, as1, ad1, hbuf, asrc, adst);

    partial_kernel<<<NB, 256, 0, stream>>>(counts, bsum);
    write_offs_kernel<<<NB, 256, 0, stream>>>(counts, bsum, offs, cursor, csrc);
    scatter_kernel<<<CNT_BLKS, 256, 0, stream>>>(ei, cursor, csrc);

    const int agg_grid = (NN + 3) / 4;

    // Layer 1 aggregation (gemm already done in fused dispatch)
    gat_agg_kernel<<<agg_grid, 256, 0, stream>>>(hbuf, asrc, adst, offs, csrc, b1, abuf);
    // Layer 2
    gemm_att_bf16_kernel<<<GEMM_GRID, 256, 0, stream>>>(abuf, wt + 2 * WPLANE, as2, ad2, hbuf, asrc, adst);
    gat_agg_kernel<<<agg_grid, 256, 0, stream>>>(hbuf, asrc, adst, offs, csrc, b2, abuf);

    // Pool + final linear
    pool_kernel<<<(NN + 31) / 32, 128, 0, stream>>>(abuf, batch, sums, cnts);
    final_kernel<<<1, NG * OC, 0, stream>>>(sums, cnts, wlin, blin, out);
}